// Round 1
// baseline (735.164 us; speedup 1.0000x reference)
//
#include <hip/hip_runtime.h>
#include <math.h>

#define QPIX 16384

// ---------------- transpose NCHW -> NHWC (per image) ----------------
__global__ __launch_bounds__(256) void k_nchw2nhwc(const float* __restrict__ in,
                                                   float* __restrict__ out, int HW) {
  int img = blockIdx.y;
  int i = blockIdx.x * 256 + threadIdx.x;   // < HW*128
  int c = i & 127, pix = i >> 7;
  out[(size_t)img * HW * 128 + (size_t)pix * 128 + c] =
      in[((size_t)img * 128 + c) * HW + pix];
}

// ---------------- generic tiled fp32 GEMM ----------------
// Out[M,N] = act( A im2col/plain @ B + bias (+resid) )
// SRC: 0 plain (A: MxK row-major, W: NxK row-major => B = W^T)
//      1 conv3x3 implicit im2col from NCHW src (C=128, H=W=128), W: 1152x128 row-major
//      2 conv3x3 implicit im2col from NHWC src,                W: 1152x128 row-major
// ACT: 0 none, 1 exact gelu
// RESMODE: 0 none, 1 NHWC resid (m*128+n), 2 NCHW resid (n*16384+m)
template <int SRC, int ACT, int RESMODE>
__global__ __launch_bounds__(256) void gemm_k(const float* __restrict__ A,
                                              const float* __restrict__ W,
                                              const float* __restrict__ bias,
                                              const float* __restrict__ resid,
                                              float* __restrict__ Out,
                                              int M, int N, int K) {
  __shared__ float As[16][64];
  __shared__ float Bs[16][128];
  const int t = threadIdx.x;
  const int m0 = blockIdx.y * 64;
  const int n0 = blockIdx.x * 128;
  const int tn16 = t & 15, tm16 = t >> 4;
  const int sm = t & 63, skq = t >> 6;     // A staging: 64 rows x 4 k-quads
  const int sn = t & 127, skq2 = t >> 7;   // B staging: 128 cols x 2 k-octets
  float acc[4][8];
#pragma unroll
  for (int i = 0; i < 4; ++i)
#pragma unroll
    for (int j = 0; j < 8; ++j) acc[i][j] = 0.f;

  for (int k0 = 0; k0 < K; k0 += 16) {
    if (SRC == 0) {
      float4 av = *(const float4*)&A[(size_t)(m0 + sm) * K + k0 + skq * 4];
      As[skq * 4 + 0][sm] = av.x; As[skq * 4 + 1][sm] = av.y;
      As[skq * 4 + 2][sm] = av.z; As[skq * 4 + 3][sm] = av.w;
      float4 b0 = *(const float4*)&W[(size_t)(n0 + sn) * K + k0 + skq2 * 8];
      float4 b1 = *(const float4*)&W[(size_t)(n0 + sn) * K + k0 + skq2 * 8 + 4];
      Bs[skq2 * 8 + 0][sn] = b0.x; Bs[skq2 * 8 + 1][sn] = b0.y;
      Bs[skq2 * 8 + 2][sn] = b0.z; Bs[skq2 * 8 + 3][sn] = b0.w;
      Bs[skq2 * 8 + 4][sn] = b1.x; Bs[skq2 * 8 + 5][sn] = b1.y;
      Bs[skq2 * 8 + 6][sn] = b1.z; Bs[skq2 * 8 + 7][sn] = b1.w;
    } else {
      const int kk9 = k0 >> 7;                 // which 3x3 tap (k0 chunks never straddle taps)
      const int cib = (k0 & 127) + skq * 4;    // input-channel base
      const int dy = kk9 / 3 - 1, dx = kk9 % 3 - 1;
      const int pix = m0 + sm;
      const int h = pix >> 7, wc = (pix & 127) + dx;
      const int hs = h + dy;
      const bool ok = (hs >= 0) && (hs < 128) && (wc >= 0) && (wc < 128);
      if (SRC == 1) {
#pragma unroll
        for (int j = 0; j < 4; ++j)
          As[skq * 4 + j][sm] = ok ? A[(size_t)(cib + j) * QPIX + hs * 128 + wc] : 0.f;
      } else {
        float4 av = ok ? *(const float4*)&A[((size_t)hs * 128 + wc) * 128 + cib]
                       : make_float4(0.f, 0.f, 0.f, 0.f);
        As[skq * 4 + 0][sm] = av.x; As[skq * 4 + 1][sm] = av.y;
        As[skq * 4 + 2][sm] = av.z; As[skq * 4 + 3][sm] = av.w;
      }
#pragma unroll
      for (int j = 0; j < 8; ++j)
        Bs[skq2 * 8 + j][sn] = W[(size_t)(k0 + skq2 * 8 + j) * 128 + n0 + sn];
    }
    __syncthreads();
#pragma unroll
    for (int kk = 0; kk < 16; ++kk) {
      float4 a = *(const float4*)&As[kk][tm16 * 4];
      float4 b0 = *(const float4*)&Bs[kk][tn16 * 8];
      float4 b1 = *(const float4*)&Bs[kk][tn16 * 8 + 4];
      float aa[4] = {a.x, a.y, a.z, a.w};
      float bb[8] = {b0.x, b0.y, b0.z, b0.w, b1.x, b1.y, b1.z, b1.w};
#pragma unroll
      for (int i = 0; i < 4; ++i)
#pragma unroll
        for (int j = 0; j < 8; ++j) acc[i][j] += aa[i] * bb[j];
    }
    __syncthreads();
  }
#pragma unroll
  for (int i = 0; i < 4; ++i) {
    const int m = m0 + tm16 * 4 + i;
#pragma unroll
    for (int j = 0; j < 8; ++j) {
      const int n = n0 + tn16 * 8 + j;
      float v = acc[i][j] + bias[n];
      if (RESMODE == 1) v += resid[(size_t)m * 128 + n];
      if (RESMODE == 2) v += resid[(size_t)n * QPIX + m];
      if (ACT == 1) v = 0.5f * v * (1.f + erff(v * 0.70710678118654752f));
      Out[(size_t)m * N + n] = v;
    }
  }
}

// ---------------- fused offset head + projection + bilinear sampling ----------------
__global__ __launch_bounds__(256) void k_sampler(const float* __restrict__ qn,
                                                 const float* __restrict__ featT,
                                                 const float* __restrict__ bpos,
                                                 const float* __restrict__ l2i,
                                                 const float* __restrict__ offw,
                                                 const float* __restrict__ offb,
                                                 float* __restrict__ sampled) {
  const int q = blockIdx.x;
  const int t = threadIdx.x;
  __shared__ float qrow[128];
  __shared__ float offv[12];
  __shared__ float cwt[4][6][4];
  __shared__ int cbs[4][6][4];
  if (t < 128) qrow[t] = qn[(size_t)q * 128 + t];
  __syncthreads();
  if (t < 12) {
    float s = offb[t];
    const float* wr = offw + t * 128;
#pragma unroll 4
    for (int c = 0; c < 128; ++c) s += qrow[c] * wr[c];
    offv[t] = 1.f / (1.f + expf(-s));
  }
  __syncthreads();
  if (t < 24) {
    const int p = t / 6, n = t - p * 6;
    const float EPSf = 1e-5f;
    float ox = offv[p * 3 + 0] * ((0.25f + EPSf) * 2.f) - (0.25f + EPSf);
    float oy = offv[p * 3 + 1] * ((0.25f + EPSf) * 2.f) - (0.25f + EPSf);
    float oz = offv[p * 3 + 2] * ((4.f + EPSf) * 2.f) - (4.f + EPSf);
    float px = bpos[q * 3 + 0] * 102.4f - 51.2f + ox;
    float py = bpos[q * 3 + 1] * 102.4f - 51.2f + oy;
    float pz = bpos[q * 3 + 2] * 8.f - 5.f + oz;
    const float* L = l2i + n * 16;
    float c0 = L[0] * px + L[1] * py + L[2] * pz + L[3];
    float c1 = L[4] * px + L[5] * py + L[6] * pz + L[7];
    float c2 = L[8] * px + L[9] * py + L[10] * pz + L[11];
    float d = fmaxf(c2, EPSf);
    float u = (c0 / d) / 704.f;
    float v = (c1 / d) / 256.f;
    float valid = (c2 > EPSf && u > 0.f && u < 1.f && v > 0.f && v < 1.f) ? 1.f : 0.f;
    float x = u * 88.f - 0.5f;
    float y = v * 32.f - 0.5f;
    float x0 = floorf(x), y0 = floorf(y);
    float wx1 = x - x0, wy1 = y - y0;
    float wx0 = 1.f - wx1, wy0 = 1.f - wy1;
#pragma unroll
    for (int k = 0; k < 4; ++k) {
      float xf = x0 + (float)(k & 1);
      float yf = y0 + (float)(k >> 1);
      bool inb = (xf >= 0.f) && (xf <= 87.f) && (yf >= 0.f) && (yf <= 31.f);
      float xc = fminf(fmaxf(xf, 0.f), 87.f);
      float yc = fminf(fmaxf(yf, 0.f), 31.f);
      int idx = ((n * 32 + (int)yc) * 88 + (int)xc) * 128;
      float wgt = ((k & 1) ? wx1 : wx0) * ((k >> 1) ? wy1 : wy0);
      cwt[p][n][k] = inb ? wgt * valid : 0.f;
      cbs[p][n][k] = idx;
    }
  }
  __syncthreads();
  const int c = t & 127;
  const int ph = t >> 7;
#pragma unroll
  for (int pp = 0; pp < 2; ++pp) {
    const int p = ph + pp * 2;
    float s = 0.f;
#pragma unroll
    for (int n = 0; n < 6; ++n)
#pragma unroll
      for (int k = 0; k < 4; ++k)
        s += cwt[p][n][k] * featT[(size_t)cbs[p][n][k] + c];
    sampled[(size_t)q * 512 + p * 128 + c] = s;
  }
}

// ---------------- instance-norm stats (deterministic 2-stage) ----------------
__global__ __launch_bounds__(256) void k_stats_partial(const float* __restrict__ a,
                                                       const float* __restrict__ b,
                                                       float* __restrict__ partial) {
  const int blk = blockIdx.x;  // 128 blocks x 128 pixels
  const int c = threadIdx.x & 127, g = threadIdx.x >> 7;
  float s = 0.f, ss = 0.f;
  for (int i = g; i < 128; i += 2) {
    const size_t pix = (size_t)blk * 128 + i;
    float v = a[pix * 128 + c];
    if (b) v += b[pix * 128 + c];
    s += v;
    ss += v * v;
  }
  __shared__ float l1[256], l2[256];
  l1[threadIdx.x] = s;
  l2[threadIdx.x] = ss;
  __syncthreads();
  if (g == 0) {
    partial[(size_t)blk * 128 + c] = l1[c] + l1[c + 128];
    partial[16384 + (size_t)blk * 128 + c] = l2[c] + l2[c + 128];
  }
}

__global__ void k_stats_final(const float* __restrict__ partial, float* __restrict__ mr) {
  const int c = threadIdx.x;  // 128 threads
  float s = 0.f, ss = 0.f;
  for (int bb = 0; bb < 128; ++bb) {
    s += partial[bb * 128 + c];
    ss += partial[16384 + bb * 128 + c];
  }
  float m = s * (1.f / 16384.f);
  float var = ss * (1.f / 16384.f) - m * m;
  mr[c] = m;
  mr[128 + c] = rsqrtf(var + 1e-5f);
}

__global__ __launch_bounds__(256) void k_apply(const float* __restrict__ a,
                                               const float* __restrict__ b,
                                               const float* __restrict__ mr,
                                               float* __restrict__ out) {
  const size_t i = (size_t)blockIdx.x * 256 + threadIdx.x;
  const int c = (int)(i & 127);
  float v = a[i];
  if (b) v += b[i];
  out[i] = (v - mr[c]) * mr[128 + c];
}

__global__ __launch_bounds__(256) void k_apply_t(const float* __restrict__ a,
                                                 const float* __restrict__ mr,
                                                 float* __restrict__ out) {
  const size_t i = (size_t)blockIdx.x * 256 + threadIdx.x;  // i = c*16384 + pix
  const int c = (int)(i >> 14);
  const int pix = (int)(i & 16383);
  out[i] = (a[(size_t)pix * 128 + c] - mr[c]) * mr[128 + c];
}

extern "C" void kernel_launch(void* const* d_in, const int* in_sizes, int n_in,
                              void* d_out, int out_size, void* d_ws, size_t ws_size,
                              hipStream_t stream) {
  const float* feats = (const float*)d_in[0];   // (6,128,32,88)
  const float* l2i   = (const float*)d_in[1];   // (1,6,4,4)
  const float* bevq  = (const float*)d_in[2];   // (1,128,128,128) NCHW
  const float* bpos  = (const float*)d_in[3];   // (1,128,128,3)
  const float* w_in  = (const float*)d_in[4];   // (3,3,128,128) HWIO == (1152,128)
  const float* b_in  = (const float*)d_in[5];
  const float* offw  = (const float*)d_in[6];   // (12,128)
  const float* offb  = (const float*)d_in[7];
  const float* w1    = (const float*)d_in[8];   // (512,512)
  const float* b1    = (const float*)d_in[9];
  const float* w2    = (const float*)d_in[10];
  const float* b2    = (const float*)d_in[11];
  const float* w3    = (const float*)d_in[12];  // (128,512)
  const float* b3    = (const float*)d_in[13];
  const float* w_out = (const float*)d_in[14];
  const float* b_out = (const float*)d_in[15];
  float* out = (float*)d_out;

  const size_t QC = (size_t)QPIX * 128;       // 2,097,152
  const size_t Q512 = (size_t)QPIX * 512;     // 8,388,608
  float* ws = (float*)d_ws;
  float* tB = ws;                   // QC   : pre-norm conv outputs (t1/t2)
  float* qC = ws + QC;              // QC   : qn -> q2 (in-place)
  float* S1 = ws + 2 * QC;          // Q512 : sampled -> x2
  float* S2 = ws + 2 * QC + Q512;   // Q512 : featT -> x1 -> x3
  float* featT = S2;                // 6*2816*128 fits at the head of S2
  float* partial = ws + 2 * QC + 2 * Q512;  // 32768
  float* mr = partial + 32768;              // 256

  dim3 blk(256);

  // features NCHW -> NHWC (dead once sampler is done; lives inside S2)
  k_nchw2nhwc<<<dim3(1408, 6), blk, 0, stream>>>(feats, featT, 2816);

  // t1 = q + conv3x3(q)  (implicit im2col from NCHW bev_query, residual NCHW)
  gemm_k<1, 0, 2><<<dim3(1, 256), blk, 0, stream>>>(bevq, w_in, b_in, bevq, tB,
                                                    QPIX, 128, 1152);
  k_stats_partial<<<128, blk, 0, stream>>>(tB, nullptr, partial);
  k_stats_final<<<1, 128, 0, stream>>>(partial, mr);
  k_apply<<<8192, blk, 0, stream>>>(tB, nullptr, mr, qC);  // qn

  // offset head + projection + bilinear gather, summed over cameras
  k_sampler<<<QPIX, blk, 0, stream>>>(qC, featT, bpos, l2i, offw, offb, S1);

  // mid MLP
  gemm_k<0, 1, 0><<<dim3(4, 256), blk, 0, stream>>>(S1, w1, b1, nullptr, S2,
                                                    QPIX, 512, 512);
  gemm_k<0, 1, 0><<<dim3(4, 256), blk, 0, stream>>>(S2, w2, b2, nullptr, S1,
                                                    QPIX, 512, 512);
  gemm_k<0, 0, 0><<<dim3(1, 256), blk, 0, stream>>>(S1, w3, b3, nullptr, S2,
                                                    QPIX, 128, 512);

  // q2 = inorm(qn + x3)   (in place into qC)
  k_stats_partial<<<128, blk, 0, stream>>>(qC, S2, partial);
  k_stats_final<<<1, 128, 0, stream>>>(partial, mr);
  k_apply<<<8192, blk, 0, stream>>>(qC, S2, mr, qC);

  // t2 = q2 + conv3x3(q2)  (implicit im2col from NHWC, residual NHWC)
  gemm_k<2, 0, 1><<<dim3(1, 256), blk, 0, stream>>>(qC, w_out, b_out, qC, tB,
                                                    QPIX, 128, 1152);
  k_stats_partial<<<128, blk, 0, stream>>>(tB, nullptr, partial);
  k_stats_final<<<1, 128, 0, stream>>>(partial, mr);
  // final inorm fused with NHWC -> NCHW output transpose
  k_apply_t<<<8192, blk, 0, stream>>>(tB, mr, out);
}

// Round 2
// 309.617 us; speedup vs baseline: 2.3744x; 2.3744x over previous
//
#include <hip/hip_runtime.h>
#include <math.h>

#define QPIX 16384

typedef __bf16 bf16x8 __attribute__((ext_vector_type(8)));
typedef float f32x4 __attribute__((ext_vector_type(4)));

__device__ __forceinline__ unsigned short f2b(float f) {
  unsigned int x = __float_as_uint(f);
  unsigned int r = (x + 0x7fff + ((x >> 16) & 1)) >> 16;
  return (unsigned short)r;
}
__device__ __forceinline__ float b2f(unsigned short u) {
  return __uint_as_float(((unsigned int)u) << 16);
}

__device__ __forceinline__ void gld_lds16(const void* g, void* l) {
  __builtin_amdgcn_global_load_lds((__attribute__((address_space(1))) void*)(g),
                                   (__attribute__((address_space(3))) void*)(l), 16, 0, 0);
}

// ---------------- conversions ----------------
__global__ __launch_bounds__(256) void k_f2b(const float* __restrict__ in,
                                             unsigned short* __restrict__ out, int n) {
  int i = blockIdx.x * 256 + threadIdx.x;
  if (i < n) out[i] = f2b(in[i]);
}

// conv weight HWIO (tap, ci, co) -> wob[co][tap*128+ci]
__global__ __launch_bounds__(256) void k_cvt_convw(const float* __restrict__ win,
                                                   unsigned short* __restrict__ wo) {
  int i = blockIdx.x * 256 + threadIdx.x;  // < 147456
  int n = i & 127, kk = i >> 7;
  int tap = kk >> 7, ci = kk & 127;
  wo[(size_t)n * 1152 + kk] = f2b(win[(size_t)tap * 16384 + ci * 128 + n]);
}

__global__ __launch_bounds__(256) void k_cvt_convw_split(const float* __restrict__ win,
                                                         unsigned short* __restrict__ whi,
                                                         unsigned short* __restrict__ wlo) {
  int i = blockIdx.x * 256 + threadIdx.x;
  int n = i & 127, kk = i >> 7;
  int tap = kk >> 7, ci = kk & 127;
  float v = win[(size_t)tap * 16384 + ci * 128 + n];
  unsigned short h = f2b(v);
  whi[(size_t)n * 1152 + kk] = h;
  wlo[(size_t)n * 1152 + kk] = f2b(v - b2f(h));
}

// bev_query NCHW fp32 -> NHWC bf16 hi/lo
__global__ __launch_bounds__(256) void k_qsplit(const float* __restrict__ q,
                                                unsigned short* __restrict__ qhi,
                                                unsigned short* __restrict__ qlo) {
  int i = blockIdx.x * 256 + threadIdx.x;  // < 2097152
  int c = i & 127, pix = i >> 7;
  float v = q[(size_t)c * QPIX + pix];
  unsigned short h = f2b(v);
  qhi[i] = h;
  qlo[i] = f2b(v - b2f(h));
}

// features NCHW fp32 -> NHWC bf16
__global__ __launch_bounds__(256) void k_nchw2nhwc_b(const float* __restrict__ in,
                                                     unsigned short* __restrict__ out, int HW) {
  int img = blockIdx.y;
  int i = blockIdx.x * 256 + threadIdx.x;  // < HW*128
  int c = i & 127, pix = i >> 7;
  out[(size_t)img * HW * 128 + (size_t)pix * 128 + c] =
      f2b(in[((size_t)img * 128 + c) * HW + pix]);
}

// ---------------- bf16 MFMA GEMM ----------------
// Out[M,N] = act( A @ Wt^T + bias (+resid) ), Wt is [N][K] bf16 row-major.
// MODE: 0 plain A [M][K] bf16; 1 conv3x3 im2col from NHWC bf16 (16384 pix, C=128);
//       2 conv3x3 im2col split-precision (A=hi, A2=lo, Wt=hi, Wt2=lo)
// ACT: 0 none, 1 exact gelu. RES: 0 none, 1 fp32 NHWC resid, 2 fp32 NCHW resid.
// OBF: 1 -> bf16 output, 0 -> fp32 output.
template <int BM, int MODE, int ACT, int RES, int OBF>
__global__ __launch_bounds__(256) void mfma_gemm(
    const unsigned short* __restrict__ A, const unsigned short* __restrict__ A2,
    const unsigned short* __restrict__ Wt, const unsigned short* __restrict__ Wt2,
    const float* __restrict__ bias, const float* __restrict__ resid,
    void* __restrict__ Out, int N, int K, const unsigned short* __restrict__ zbuf) {
  constexpr int WROWS = BM / 2;   // rows per wave tile
  constexpr int MI = BM / 32;     // 16-row frags per wave
  __shared__ unsigned short As[BM * 64];
  __shared__ unsigned short Bs[128 * 64];
  __shared__ unsigned short As2[(MODE == 2) ? BM * 64 : 1];
  __shared__ unsigned short Bs2[(MODE == 2) ? 128 * 64 : 1];

  const int t = threadIdx.x;
  const int lane = t & 63, w = t >> 6;
  const int wr = w >> 1, wc = w & 1;
  const int n0 = blockIdx.x * 128;
  const int m0 = blockIdx.y * BM;

  const int lrow = lane >> 3;          // staging: row within 8-row chunk
  const int akk = (lane & 7) * 8;      // staging: k element offset (16B)
  const int arow_l = wr * WROWS + (lane & 15);
  const int brow_l = wc * 64 + (lane & 15);
  const int klane = (lane >> 4) * 8;

  f32x4 acc[MI][4];
#pragma unroll
  for (int i = 0; i < MI; ++i)
#pragma unroll
    for (int j = 0; j < 4; ++j) acc[i][j] = (f32x4){0.f, 0.f, 0.f, 0.f};

  for (int k0 = 0; k0 < K; k0 += 64) {
    // ---- stage A (BM x 64) ----
#pragma unroll
    for (int q = 0; q < BM / 32; ++q) {
      const int r0 = w * (BM / 4) + q * 8;
      const int arow = r0 + lrow;
      const unsigned short* asrc;
      const unsigned short* asrc2 = zbuf;
      if (MODE == 0) {
        asrc = A + (size_t)(m0 + arow) * K + k0 + akk;
      } else {
        const int tap = k0 >> 7;
        const int dy = tap / 3 - 1, dx = tap % 3 - 1;
        const int pix = m0 + arow;
        const int hs = (pix >> 7) + dy;
        const int xs = (pix & 127) + dx;
        const bool ok = (hs >= 0) && (hs < 128) && (xs >= 0) && (xs < 128);
        const size_t srcoff = (size_t)((hs << 7) | (xs & 127)) * 128 + (k0 & 127) + akk;
        asrc = ok ? A + srcoff : zbuf;
        if (MODE == 2) asrc2 = ok ? A2 + srcoff : zbuf;
      }
      gld_lds16(asrc, &As[r0 * 64]);
      if (MODE == 2) gld_lds16(asrc2, &As2[r0 * 64]);
    }
    // ---- stage B (128 x 64) ----
#pragma unroll
    for (int q = 0; q < 4; ++q) {
      const int r0 = w * 32 + q * 8;
      const int brow = r0 + lrow;
      gld_lds16(Wt + (size_t)(n0 + brow) * K + k0 + akk, &Bs[r0 * 64]);
      if (MODE == 2)
        gld_lds16(Wt2 + (size_t)(n0 + brow) * K + k0 + akk, &Bs2[r0 * 64]);
    }
    __syncthreads();
#pragma unroll
    for (int ks = 0; ks < 64; ks += 32) {
      bf16x8 af[MI], bfv[4];
#pragma unroll
      for (int i = 0; i < MI; ++i)
        af[i] = *(const bf16x8*)&As[(arow_l + i * 16) * 64 + ks + klane];
#pragma unroll
      for (int j = 0; j < 4; ++j)
        bfv[j] = *(const bf16x8*)&Bs[(brow_l + j * 16) * 64 + ks + klane];
#pragma unroll
      for (int i = 0; i < MI; ++i)
#pragma unroll
        for (int j = 0; j < 4; ++j)
          acc[i][j] = __builtin_amdgcn_mfma_f32_16x16x32_bf16(af[i], bfv[j], acc[i][j], 0, 0, 0);
      if (MODE == 2) {
        bf16x8 af2[MI], bf2[4];
#pragma unroll
        for (int i = 0; i < MI; ++i)
          af2[i] = *(const bf16x8*)&As2[(arow_l + i * 16) * 64 + ks + klane];
#pragma unroll
        for (int j = 0; j < 4; ++j)
          bf2[j] = *(const bf16x8*)&Bs2[(brow_l + j * 16) * 64 + ks + klane];
#pragma unroll
        for (int i = 0; i < MI; ++i)
#pragma unroll
          for (int j = 0; j < 4; ++j) {
            acc[i][j] = __builtin_amdgcn_mfma_f32_16x16x32_bf16(af[i], bf2[j], acc[i][j], 0, 0, 0);
            acc[i][j] = __builtin_amdgcn_mfma_f32_16x16x32_bf16(af2[i], bfv[j], acc[i][j], 0, 0, 0);
          }
      }
    }
    __syncthreads();
  }
  // ---- epilogue ----
#pragma unroll
  for (int i = 0; i < MI; ++i) {
    const int mrow = m0 + wr * WROWS + i * 16 + (lane >> 4) * 4;
#pragma unroll
    for (int j = 0; j < 4; ++j) {
      const int col = n0 + wc * 64 + j * 16 + (lane & 15);
      const float bz = bias[col];
#pragma unroll
      for (int r = 0; r < 4; ++r) {
        const int m = mrow + r;
        float v = acc[i][j][r] + bz;
        if (RES == 1) v += resid[(size_t)m * 128 + col];
        if (RES == 2) v += resid[(size_t)col * QPIX + m];
        if (ACT == 1) v = 0.5f * v * (1.f + erff(v * 0.70710678118654752f));
        if (OBF)
          ((unsigned short*)Out)[(size_t)m * N + col] = f2b(v);
        else
          ((float*)Out)[(size_t)m * N + col] = v;
      }
    }
  }
}

// ---------------- fused offset head + projection + bilinear sampling ----------------
__global__ __launch_bounds__(256) void k_sampler(const float* __restrict__ qn,
                                                 const unsigned short* __restrict__ featT,
                                                 const float* __restrict__ bpos,
                                                 const float* __restrict__ l2i,
                                                 const float* __restrict__ offw,
                                                 const float* __restrict__ offb,
                                                 unsigned short* __restrict__ sampled) {
  const int q = blockIdx.x;
  const int t = threadIdx.x;
  __shared__ float qrow[128];
  __shared__ float offv[12];
  __shared__ float cwt[4][6][4];
  __shared__ int cbs[4][6][4];
  if (t < 128) qrow[t] = qn[(size_t)q * 128 + t];
  __syncthreads();
  if (t < 12) {
    float s = offb[t];
    const float* wr = offw + t * 128;
#pragma unroll 4
    for (int c = 0; c < 128; ++c) s += qrow[c] * wr[c];
    offv[t] = 1.f / (1.f + expf(-s));
  }
  __syncthreads();
  if (t < 24) {
    const int p = t / 6, n = t - p * 6;
    const float EPSf = 1e-5f;
    float ox = offv[p * 3 + 0] * ((0.25f + EPSf) * 2.f) - (0.25f + EPSf);
    float oy = offv[p * 3 + 1] * ((0.25f + EPSf) * 2.f) - (0.25f + EPSf);
    float oz = offv[p * 3 + 2] * ((4.f + EPSf) * 2.f) - (4.f + EPSf);
    float px = bpos[q * 3 + 0] * 102.4f - 51.2f + ox;
    float py = bpos[q * 3 + 1] * 102.4f - 51.2f + oy;
    float pz = bpos[q * 3 + 2] * 8.f - 5.f + oz;
    const float* L = l2i + n * 16;
    float c0 = L[0] * px + L[1] * py + L[2] * pz + L[3];
    float c1 = L[4] * px + L[5] * py + L[6] * pz + L[7];
    float c2 = L[8] * px + L[9] * py + L[10] * pz + L[11];
    float d = fmaxf(c2, EPSf);
    float u = (c0 / d) / 704.f;
    float v = (c1 / d) / 256.f;
    float valid = (c2 > EPSf && u > 0.f && u < 1.f && v > 0.f && v < 1.f) ? 1.f : 0.f;
    float x = u * 88.f - 0.5f;
    float y = v * 32.f - 0.5f;
    float x0 = floorf(x), y0 = floorf(y);
    float wx1 = x - x0, wy1 = y - y0;
    float wx0 = 1.f - wx1, wy0 = 1.f - wy1;
#pragma unroll
    for (int k = 0; k < 4; ++k) {
      float xf = x0 + (float)(k & 1);
      float yf = y0 + (float)(k >> 1);
      bool inb = (xf >= 0.f) && (xf <= 87.f) && (yf >= 0.f) && (yf <= 31.f);
      float xc = fminf(fmaxf(xf, 0.f), 87.f);
      float yc = fminf(fmaxf(yf, 0.f), 31.f);
      int idx = ((n * 32 + (int)yc) * 88 + (int)xc) * 128;
      float wgt = ((k & 1) ? wx1 : wx0) * ((k >> 1) ? wy1 : wy0);
      cwt[p][n][k] = inb ? wgt * valid : 0.f;
      cbs[p][n][k] = idx;
    }
  }
  __syncthreads();
  const int c = t & 127;
  const int ph = t >> 7;
#pragma unroll
  for (int pp = 0; pp < 2; ++pp) {
    const int p = ph + pp * 2;
    float s = 0.f;
#pragma unroll
    for (int n = 0; n < 6; ++n) {
      float w0 = cwt[p][n][0], w1 = cwt[p][n][1], w2 = cwt[p][n][2], w3 = cwt[p][n][3];
      if (w0 + w1 + w2 + w3 != 0.f) {
        s += w0 * b2f(featT[(size_t)cbs[p][n][0] + c]) +
             w1 * b2f(featT[(size_t)cbs[p][n][1] + c]) +
             w2 * b2f(featT[(size_t)cbs[p][n][2] + c]) +
             w3 * b2f(featT[(size_t)cbs[p][n][3] + c]);
      }
    }
    sampled[(size_t)q * 512 + p * 128 + c] = f2b(s);
  }
}

// ---------------- instance-norm stats (deterministic 2-stage) ----------------
__global__ __launch_bounds__(256) void k_stats_partial(const float* __restrict__ a,
                                                       const float* __restrict__ b,
                                                       float* __restrict__ partial) {
  const int blk = blockIdx.x;
  const int c = threadIdx.x & 127, g = threadIdx.x >> 7;
  float s = 0.f, ss = 0.f;
  for (int i = g; i < 128; i += 2) {
    const size_t pix = (size_t)blk * 128 + i;
    float v = a[pix * 128 + c];
    if (b) v += b[pix * 128 + c];
    s += v;
    ss += v * v;
  }
  __shared__ float l1[256], l2[256];
  l1[threadIdx.x] = s;
  l2[threadIdx.x] = ss;
  __syncthreads();
  if (g == 0) {
    partial[(size_t)blk * 128 + c] = l1[c] + l1[c + 128];
    partial[16384 + (size_t)blk * 128 + c] = l2[c] + l2[c + 128];
  }
}

__global__ void k_stats_final(const float* __restrict__ partial, float* __restrict__ mr) {
  const int c = threadIdx.x;
  float s = 0.f, ss = 0.f;
  for (int bb = 0; bb < 128; ++bb) {
    s += partial[bb * 128 + c];
    ss += partial[16384 + bb * 128 + c];
  }
  float m = s * (1.f / 16384.f);
  float var = ss * (1.f / 16384.f) - m * m;
  mr[c] = m;
  mr[128 + c] = rsqrtf(var + 1e-5f);
}

__global__ __launch_bounds__(256) void k_apply(const float* __restrict__ a,
                                               const float* __restrict__ b,
                                               const float* __restrict__ mr,
                                               float* __restrict__ out) {
  const size_t i = (size_t)blockIdx.x * 256 + threadIdx.x;
  const int c = (int)(i & 127);
  float v = a[i];
  if (b) v += b[i];
  out[i] = (v - mr[c]) * mr[128 + c];
}

__global__ __launch_bounds__(256) void k_apply2(const float* __restrict__ a,
                                                const float* __restrict__ b,
                                                const float* __restrict__ mr,
                                                float* __restrict__ outf,
                                                unsigned short* __restrict__ outb) {
  const size_t i = (size_t)blockIdx.x * 256 + threadIdx.x;
  const int c = (int)(i & 127);
  float v = (a[i] + b[i] - mr[c]) * mr[128 + c];
  outf[i] = v;
  outb[i] = f2b(v);
}

__global__ __launch_bounds__(256) void k_apply_t(const float* __restrict__ a,
                                                 const float* __restrict__ mr,
                                                 float* __restrict__ out) {
  const size_t i = (size_t)blockIdx.x * 256 + threadIdx.x;  // i = c*16384 + pix
  const int c = (int)(i >> 14);
  const int pix = (int)(i & 16383);
  out[i] = (a[(size_t)pix * 128 + c] - mr[c]) * mr[128 + c];
}

extern "C" void kernel_launch(void* const* d_in, const int* in_sizes, int n_in,
                              void* d_out, int out_size, void* d_ws, size_t ws_size,
                              hipStream_t stream) {
  const float* feats = (const float*)d_in[0];
  const float* l2i   = (const float*)d_in[1];
  const float* bevq  = (const float*)d_in[2];
  const float* bpos  = (const float*)d_in[3];
  const float* w_in  = (const float*)d_in[4];
  const float* b_in  = (const float*)d_in[5];
  const float* offw  = (const float*)d_in[6];
  const float* offb  = (const float*)d_in[7];
  const float* w1    = (const float*)d_in[8];
  const float* b1    = (const float*)d_in[9];
  const float* w2    = (const float*)d_in[10];
  const float* b2    = (const float*)d_in[11];
  const float* w3    = (const float*)d_in[12];
  const float* b3    = (const float*)d_in[13];
  const float* w_out = (const float*)d_in[14];
  const float* b_out = (const float*)d_in[15];
  float* out = (float*)d_out;

  const size_t QC = (size_t)QPIX * 128;
  float* ws = (float*)d_ws;
  float* tB = ws;                        // 2097152
  float* qC = tB + QC;                   // 2097152
  float* x3 = qC + QC;                   // 2097152
  float* partial = x3 + QC;              // 32768
  float* mr = partial + 32768;           // 256
  float* zbufF = mr + 256;               // 64
  unsigned short* us = (unsigned short*)(zbufF + 64);
  unsigned short* S1b = us;              // 8388608 (sampled -> x2)
  unsigned short* S2b = S1b + 8388608;   // 8388608 (x1)
  unsigned short* featTb = S2b + 8388608;       // 2162688
  unsigned short* qhi = featTb + 2162688;       // 2097152 (later reused as q2b)
  unsigned short* qlo = qhi + 2097152;          // 2097152
  unsigned short* w1b = qlo + 2097152;          // 262144
  unsigned short* w2b = w1b + 262144;           // 262144
  unsigned short* w3b = w2b + 262144;           // 65536
  unsigned short* wob = w3b + 65536;            // 147456
  unsigned short* wibh = wob + 147456;          // 147456
  unsigned short* wibl = wibh + 147456;         // 147456
  const unsigned short* zb = (const unsigned short*)zbufF;

  dim3 blk(256);
  hipMemsetAsync(zbufF, 0, 256, stream);

  // input conversions
  k_nchw2nhwc_b<<<dim3(1408, 6), blk, 0, stream>>>(feats, featTb, 2816);
  k_f2b<<<1024, blk, 0, stream>>>(w1, w1b, 262144);
  k_f2b<<<1024, blk, 0, stream>>>(w2, w2b, 262144);
  k_f2b<<<256, blk, 0, stream>>>(w3, w3b, 65536);
  k_cvt_convw<<<576, blk, 0, stream>>>(w_out, wob);
  k_cvt_convw_split<<<576, blk, 0, stream>>>(w_in, wibh, wibl);
  k_qsplit<<<8192, blk, 0, stream>>>(bevq, qhi, qlo);

  // t1 = q + conv3x3(q)  (split-precision bf16 MFMA, ~fp32 accurate)
  mfma_gemm<64, 2, 0, 2, 0><<<dim3(1, 256), blk, 0, stream>>>(
      qhi, qlo, wibh, wibl, b_in, bevq, tB, 128, 1152, zb);
  k_stats_partial<<<128, blk, 0, stream>>>(tB, nullptr, partial);
  k_stats_final<<<1, 128, 0, stream>>>(partial, mr);
  k_apply<<<8192, blk, 0, stream>>>(tB, nullptr, mr, qC);  // qn fp32

  // offset head + projection + bilinear gather (bf16 features, bf16 out)
  k_sampler<<<QPIX, blk, 0, stream>>>(qC, featTb, bpos, l2i, offw, offb, S1b);

  // mid MLP (bf16 MFMA)
  mfma_gemm<128, 0, 1, 0, 1><<<dim3(4, 128), blk, 0, stream>>>(
      S1b, nullptr, w1b, nullptr, b1, nullptr, S2b, 512, 512, zb);
  mfma_gemm<128, 0, 1, 0, 1><<<dim3(4, 128), blk, 0, stream>>>(
      S2b, nullptr, w2b, nullptr, b2, nullptr, S1b, 512, 512, zb);
  mfma_gemm<64, 0, 0, 0, 0><<<dim3(1, 256), blk, 0, stream>>>(
      S1b, nullptr, w3b, nullptr, b3, nullptr, x3, 128, 512, zb);

  // q2 = inorm(qn + x3); also emit bf16 copy for conv2 (reuse qhi)
  k_stats_partial<<<128, blk, 0, stream>>>(qC, x3, partial);
  k_stats_final<<<1, 128, 0, stream>>>(partial, mr);
  k_apply2<<<8192, blk, 0, stream>>>(qC, x3, mr, qC, qhi);

  // t2 = q2 + conv3x3(q2)  (bf16 MFMA im2col)
  mfma_gemm<64, 1, 0, 1, 0><<<dim3(1, 256), blk, 0, stream>>>(
      qhi, nullptr, wob, nullptr, b_out, qC, tB, 128, 1152, zb);
  k_stats_partial<<<128, blk, 0, stream>>>(tB, nullptr, partial);
  k_stats_final<<<1, 128, 0, stream>>>(partial, mr);
  k_apply_t<<<8192, blk, 0, stream>>>(tB, mr, out);
}

// Round 3
// 264.392 us; speedup vs baseline: 2.7806x; 1.1711x over previous
//
#include <hip/hip_runtime.h>
#include <math.h>

#define QPIX 16384

typedef __bf16 bf16x8 __attribute__((ext_vector_type(8)));
typedef float f32x4 __attribute__((ext_vector_type(4)));

__device__ __forceinline__ unsigned short f2b(float f) {
  unsigned int x = __float_as_uint(f);
  unsigned int r = (x + 0x7fff + ((x >> 16) & 1)) >> 16;
  return (unsigned short)r;
}
__device__ __forceinline__ float b2f(unsigned short u) {
  return __uint_as_float(((unsigned int)u) << 16);
}

__device__ __forceinline__ void gld_lds16(const void* g, void* l) {
  __builtin_amdgcn_global_load_lds((__attribute__((address_space(1))) void*)(g),
                                   (__attribute__((address_space(3))) void*)(l), 16, 0, 0);
}

// ---------------- LDS-tiled transpose+convert: [C=128][HW] f32 -> [HW][128] bf16 ----------------
__global__ __launch_bounds__(256) void k_t2b(const float* __restrict__ in,
                                             unsigned short* __restrict__ out, int HW) {
  __shared__ float tile[128][33];
  const int t = threadIdx.x;
  const int pb = blockIdx.x * 32;
  const int img = blockIdx.y;
  const int p = t & 31, cg = t >> 5;
#pragma unroll
  for (int ci = 0; ci < 16; ++ci) {
    const int c = cg * 16 + ci;
    tile[c][p] = in[((size_t)img * 128 + c) * HW + pb + p];
  }
  __syncthreads();
  const int c2 = t & 127, pw = t >> 7;
#pragma unroll
  for (int pp = pw; pp < 32; pp += 2)
    out[(size_t)img * HW * 128 + (size_t)(pb + pp) * 128 + c2] = f2b(tile[c2][pp]);
}

// same but split hi/lo (for conv1 split-precision input)
__global__ __launch_bounds__(256) void k_t2b_split(const float* __restrict__ in,
                                                   unsigned short* __restrict__ ohi,
                                                   unsigned short* __restrict__ olo) {
  __shared__ float tile[128][33];
  const int t = threadIdx.x;
  const int pb = blockIdx.x * 32;
  const int p = t & 31, cg = t >> 5;
#pragma unroll
  for (int ci = 0; ci < 16; ++ci) {
    const int c = cg * 16 + ci;
    tile[c][p] = in[(size_t)c * QPIX + pb + p];
  }
  __syncthreads();
  const int c2 = t & 127, pw = t >> 7;
#pragma unroll
  for (int pp = pw; pp < 32; pp += 2) {
    float v = tile[c2][pp];
    unsigned short h = f2b(v);
    ohi[(size_t)(pb + pp) * 128 + c2] = h;
    olo[(size_t)(pb + pp) * 128 + c2] = f2b(v - b2f(h));
  }
}

// ---------------- all weight conversions in one dispatch ----------------
__global__ __launch_bounds__(256) void k_wcvt(
    const float* __restrict__ w1, const float* __restrict__ w2,
    const float* __restrict__ w3, const float* __restrict__ wo,
    const float* __restrict__ wi, unsigned short* __restrict__ w1b,
    unsigned short* __restrict__ w2b, unsigned short* __restrict__ w3b,
    unsigned short* __restrict__ wob, unsigned short* __restrict__ wibh,
    unsigned short* __restrict__ wibl) {
  const int b = blockIdx.x, t = threadIdx.x;
  if (b < 1024) {
    int i = b * 256 + t;
    w1b[i] = f2b(w1[i]);
  } else if (b < 2048) {
    int i = (b - 1024) * 256 + t;
    w2b[i] = f2b(w2[i]);
  } else if (b < 2304) {
    int i = (b - 2048) * 256 + t;
    w3b[i] = f2b(w3[i]);
  } else if (b < 2880) {
    int i = (b - 2304) * 256 + t;
    int n = i & 127, kk = i >> 7;
    int tap = kk >> 7, ci = kk & 127;
    wob[(size_t)n * 1152 + kk] = f2b(wo[(size_t)tap * 16384 + ci * 128 + n]);
  } else {
    int i = (b - 2880) * 256 + t;
    int n = i & 127, kk = i >> 7;
    int tap = kk >> 7, ci = kk & 127;
    float v = wi[(size_t)tap * 16384 + ci * 128 + n];
    unsigned short h = f2b(v);
    wibh[(size_t)n * 1152 + kk] = h;
    wibl[(size_t)n * 1152 + kk] = f2b(v - b2f(h));
  }
}

// ---------------- bf16 MFMA GEMM (optionally K-split across blockIdx.z) ----------------
// Out[M,N] = act( A @ Wt^T + bias (+resid) ), Wt is [N][K] bf16 row-major.
// MODE: 0 plain A [M][K]; 1 conv3x3 im2col from NHWC bf16; 2 conv im2col split-precision.
// ACT: 0 none, 1 exact gelu. RES: 0 none, 1 fp32 NHWC resid, 2 fp32 NCHW resid (z==0 only).
// OBF: 1 bf16 output, 0 fp32. blockIdx.z selects K-half: z=0 -> Out/bias(+resid), z=1 -> OutB/zbias.
template <int BM, int MODE, int ACT, int RES, int OBF>
__global__ __launch_bounds__(256) void mfma_gemm(
    const unsigned short* __restrict__ A, const unsigned short* __restrict__ A2,
    const unsigned short* __restrict__ Wt, const unsigned short* __restrict__ Wt2,
    const float* __restrict__ bias, const float* __restrict__ zbias,
    const float* __restrict__ resid, void* __restrict__ Out, void* __restrict__ OutB,
    int N, int K, int khalf, const unsigned short* __restrict__ zbuf) {
  constexpr int WROWS = BM / 2;
  constexpr int MI = BM / 32;
  __shared__ unsigned short As[BM * 64];
  __shared__ unsigned short Bs[128 * 64];
  __shared__ unsigned short As2[(MODE == 2) ? BM * 64 : 1];
  __shared__ unsigned short Bs2[(MODE == 2) ? 128 * 64 : 1];

  const int t = threadIdx.x;
  const int lane = t & 63, w = t >> 6;
  const int wr = w >> 1, wc = w & 1;
  const int n0 = blockIdx.x * 128;
  const int m0 = blockIdx.y * BM;
  const int kbase = blockIdx.z * khalf;

  const int lrow = lane >> 3;
  const int akk = (lane & 7) * 8;
  const int arow_l = wr * WROWS + (lane & 15);
  const int brow_l = wc * 64 + (lane & 15);
  const int klane = (lane >> 4) * 8;

  f32x4 acc[MI][4];
#pragma unroll
  for (int i = 0; i < MI; ++i)
#pragma unroll
    for (int j = 0; j < 4; ++j) acc[i][j] = (f32x4){0.f, 0.f, 0.f, 0.f};

  for (int k0 = kbase; k0 < kbase + khalf; k0 += 64) {
#pragma unroll
    for (int q = 0; q < BM / 32; ++q) {
      const int r0 = w * (BM / 4) + q * 8;
      const int arow = r0 + lrow;
      const unsigned short* asrc;
      const unsigned short* asrc2 = zbuf;
      if (MODE == 0) {
        asrc = A + (size_t)(m0 + arow) * K + k0 + akk;
      } else {
        const int tap = k0 >> 7;
        const int dy = tap / 3 - 1, dx = tap % 3 - 1;
        const int pix = m0 + arow;
        const int hs = (pix >> 7) + dy;
        const int xs = (pix & 127) + dx;
        const bool ok = (hs >= 0) && (hs < 128) && (xs >= 0) && (xs < 128);
        const size_t srcoff = (size_t)((hs << 7) | (xs & 127)) * 128 + (k0 & 127) + akk;
        asrc = ok ? A + srcoff : zbuf;
        if (MODE == 2) asrc2 = ok ? A2 + srcoff : zbuf;
      }
      gld_lds16(asrc, &As[r0 * 64]);
      if (MODE == 2) gld_lds16(asrc2, &As2[r0 * 64]);
    }
#pragma unroll
    for (int q = 0; q < 4; ++q) {
      const int r0 = w * 32 + q * 8;
      const int brow = r0 + lrow;
      gld_lds16(Wt + (size_t)(n0 + brow) * K + k0 + akk, &Bs[r0 * 64]);
      if (MODE == 2)
        gld_lds16(Wt2 + (size_t)(n0 + brow) * K + k0 + akk, &Bs2[r0 * 64]);
    }
    __syncthreads();
#pragma unroll
    for (int ks = 0; ks < 64; ks += 32) {
      bf16x8 af[MI], bfv[4];
#pragma unroll
      for (int i = 0; i < MI; ++i)
        af[i] = *(const bf16x8*)&As[(arow_l + i * 16) * 64 + ks + klane];
#pragma unroll
      for (int j = 0; j < 4; ++j)
        bfv[j] = *(const bf16x8*)&Bs[(brow_l + j * 16) * 64 + ks + klane];
#pragma unroll
      for (int i = 0; i < MI; ++i)
#pragma unroll
        for (int j = 0; j < 4; ++j)
          acc[i][j] = __builtin_amdgcn_mfma_f32_16x16x32_bf16(af[i], bfv[j], acc[i][j], 0, 0, 0);
      if (MODE == 2) {
        bf16x8 af2[MI], bf2[4];
#pragma unroll
        for (int i = 0; i < MI; ++i)
          af2[i] = *(const bf16x8*)&As2[(arow_l + i * 16) * 64 + ks + klane];
#pragma unroll
        for (int j = 0; j < 4; ++j)
          bf2[j] = *(const bf16x8*)&Bs2[(brow_l + j * 16) * 64 + ks + klane];
#pragma unroll
        for (int i = 0; i < MI; ++i)
#pragma unroll
          for (int j = 0; j < 4; ++j) {
            acc[i][j] = __builtin_amdgcn_mfma_f32_16x16x32_bf16(af[i], bf2[j], acc[i][j], 0, 0, 0);
            acc[i][j] = __builtin_amdgcn_mfma_f32_16x16x32_bf16(af2[i], bfv[j], acc[i][j], 0, 0, 0);
          }
      }
    }
    __syncthreads();
  }
  const bool zh = (blockIdx.z != 0);
  const float* bvec = zh ? zbias : bias;
  void* outp = zh ? OutB : Out;
#pragma unroll
  for (int i = 0; i < MI; ++i) {
    const int mrow = m0 + wr * WROWS + i * 16 + (lane >> 4) * 4;
#pragma unroll
    for (int j = 0; j < 4; ++j) {
      const int col = n0 + wc * 64 + j * 16 + (lane & 15);
      const float bz = bvec[col];
#pragma unroll
      for (int r = 0; r < 4; ++r) {
        const int m = mrow + r;
        float v = acc[i][j][r] + bz;
        if (RES == 1) {
          if (!zh) v += resid[(size_t)m * 128 + col];
        }
        if (RES == 2) {
          if (!zh) v += resid[(size_t)col * QPIX + m];
        }
        if (ACT == 1) v = 0.5f * v * (1.f + erff(v * 0.70710678118654752f));
        if (OBF)
          ((unsigned short*)outp)[(size_t)m * N + col] = f2b(v);
        else
          ((float*)outp)[(size_t)m * N + col] = v;
      }
    }
  }
}

// ---------------- offset head: off[16384][12] = sigmoid(qn @ offw^T + offb) ----------------
__global__ __launch_bounds__(256) void k_offsets(const float* __restrict__ qn,
                                                 const float* __restrict__ offw,
                                                 const float* __restrict__ offb,
                                                 float* __restrict__ off) {
  __shared__ float ldsq[128 * 130];
  __shared__ float wT[128 * 12];
  __shared__ float bl[12];
  const int t = threadIdx.x;
  const int qb = blockIdx.x * 128;
  for (int i = t; i < 1536; i += 256) wT[(i & 127) * 12 + (i >> 7)] = offw[i];
  if (t < 12) bl[t] = offb[t];
#pragma unroll
  for (int j = 0; j < 32; ++j) {
    const int e = j * 512 + t * 2;
    float2 v = *(const float2*)&qn[(size_t)qb * 128 + e];
    *(float2*)&ldsq[(e >> 7) * 130 + (e & 127)] = v;
  }
  __syncthreads();
  const int qlc = t & 127, oh = t >> 7;
  float acc[6];
#pragma unroll
  for (int o = 0; o < 6; ++o) acc[o] = bl[oh * 6 + o];
  for (int c = 0; c < 128; ++c) {
    float qv = ldsq[qlc * 130 + c];
#pragma unroll
    for (int o = 0; o < 6; ++o) acc[o] += qv * wT[c * 12 + oh * 6 + o];
  }
#pragma unroll
  for (int o = 0; o < 6; ++o)
    off[(size_t)(qb + qlc) * 12 + oh * 6 + o] = 1.f / (1.f + expf(-acc[o]));
}

// ---------------- projection + vectorized bilinear gather ----------------
__global__ __launch_bounds__(256) void k_gather(const float* __restrict__ off,
                                                const unsigned short* __restrict__ featT,
                                                const float* __restrict__ bpos,
                                                const float* __restrict__ l2i,
                                                unsigned short* __restrict__ sampled) {
  const int q = blockIdx.x;
  const int t = threadIdx.x;
  __shared__ float cwt[4][6][4];
  __shared__ int cbs[4][6][4];
  if (t < 24) {
    const int p = t / 6, n = t - p * 6;
    const float EPSf = 1e-5f;
    float o0 = off[q * 12 + p * 3 + 0];
    float o1 = off[q * 12 + p * 3 + 1];
    float o2 = off[q * 12 + p * 3 + 2];
    float ox = o0 * ((0.25f + EPSf) * 2.f) - (0.25f + EPSf);
    float oy = o1 * ((0.25f + EPSf) * 2.f) - (0.25f + EPSf);
    float oz = o2 * ((4.f + EPSf) * 2.f) - (4.f + EPSf);
    float px = bpos[q * 3 + 0] * 102.4f - 51.2f + ox;
    float py = bpos[q * 3 + 1] * 102.4f - 51.2f + oy;
    float pz = bpos[q * 3 + 2] * 8.f - 5.f + oz;
    const float* L = l2i + n * 16;
    float c0 = L[0] * px + L[1] * py + L[2] * pz + L[3];
    float c1 = L[4] * px + L[5] * py + L[6] * pz + L[7];
    float c2 = L[8] * px + L[9] * py + L[10] * pz + L[11];
    float d = fmaxf(c2, EPSf);
    float u = (c0 / d) / 704.f;
    float v = (c1 / d) / 256.f;
    float valid = (c2 > EPSf && u > 0.f && u < 1.f && v > 0.f && v < 1.f) ? 1.f : 0.f;
    float x = u * 88.f - 0.5f;
    float y = v * 32.f - 0.5f;
    float x0 = floorf(x), y0 = floorf(y);
    float wx1 = x - x0, wy1 = y - y0;
    float wx0 = 1.f - wx1, wy0 = 1.f - wy1;
#pragma unroll
    for (int k = 0; k < 4; ++k) {
      float xf = x0 + (float)(k & 1);
      float yf = y0 + (float)(k >> 1);
      bool inb = (xf >= 0.f) && (xf <= 87.f) && (yf >= 0.f) && (yf <= 31.f);
      float xc = fminf(fmaxf(xf, 0.f), 87.f);
      float yc = fminf(fmaxf(yf, 0.f), 31.f);
      int idx = ((n * 32 + (int)yc) * 88 + (int)xc) * 128;
      float wgt = ((k & 1) ? wx1 : wx0) * ((k >> 1) ? wy1 : wy0);
      cwt[p][n][k] = inb ? wgt * valid : 0.f;
      cbs[p][n][k] = idx;
    }
  }
  __syncthreads();
  const int p = t >> 6;
  const int lane = t & 63;
  const int half = lane >> 5, quad = lane & 31;
  float s0 = 0.f, s1 = 0.f, s2 = 0.f, s3 = 0.f;
#pragma unroll
  for (int cc = 0; cc < 3; ++cc) {
    const int n = half * 3 + cc;
    float wv0 = cwt[p][n][0], wv1 = cwt[p][n][1], wv2 = cwt[p][n][2], wv3 = cwt[p][n][3];
    if (wv0 + wv1 + wv2 + wv3 != 0.f) {
      const float wv[4] = {wv0, wv1, wv2, wv3};
#pragma unroll
      for (int k = 0; k < 4; ++k) {
        ushort4 v = *(const ushort4*)&featT[(size_t)cbs[p][n][k] + quad * 4];
        s0 += wv[k] * b2f(v.x);
        s1 += wv[k] * b2f(v.y);
        s2 += wv[k] * b2f(v.z);
        s3 += wv[k] * b2f(v.w);
      }
    }
  }
  s0 += __shfl_xor(s0, 32);
  s1 += __shfl_xor(s1, 32);
  s2 += __shfl_xor(s2, 32);
  s3 += __shfl_xor(s3, 32);
  if (half == 0) {
    ushort4 o;
    o.x = f2b(s0);
    o.y = f2b(s1);
    o.z = f2b(s2);
    o.w = f2b(s3);
    *(ushort4*)&sampled[(size_t)q * 512 + p * 128 + quad * 4] = o;
  }
}

// ---------------- instance-norm stats (deterministic 2-stage) ----------------
__global__ __launch_bounds__(256) void k_stats_partial(const float* __restrict__ a,
                                                       const float* __restrict__ b,
                                                       float* __restrict__ partial) {
  const int blk = blockIdx.x;
  const int c = threadIdx.x & 127, g = threadIdx.x >> 7;
  float s = 0.f, ss = 0.f;
  for (int i = g; i < 128; i += 2) {
    const size_t pix = (size_t)blk * 128 + i;
    float v = a[pix * 128 + c];
    if (b) v += b[pix * 128 + c];
    s += v;
    ss += v * v;
  }
  __shared__ float l1[256], l2[256];
  l1[threadIdx.x] = s;
  l2[threadIdx.x] = ss;
  __syncthreads();
  if (g == 0) {
    partial[(size_t)blk * 128 + c] = l1[c] + l1[c + 128];
    partial[16384 + (size_t)blk * 128 + c] = l2[c] + l2[c + 128];
  }
}

__global__ void k_stats_final(const float* __restrict__ partial, float* __restrict__ mr) {
  const int c = threadIdx.x;
  float s = 0.f, ss = 0.f;
  for (int bb = 0; bb < 128; ++bb) {
    s += partial[bb * 128 + c];
    ss += partial[16384 + bb * 128 + c];
  }
  float m = s * (1.f / 16384.f);
  float var = ss * (1.f / 16384.f) - m * m;
  mr[c] = m;
  mr[128 + c] = rsqrtf(var + 1e-5f);
}

__global__ __launch_bounds__(256) void k_apply(const float* __restrict__ a,
                                               const float* __restrict__ b,
                                               const float* __restrict__ mr,
                                               float* __restrict__ out) {
  const size_t i = (size_t)blockIdx.x * 256 + threadIdx.x;
  const int c = (int)(i & 127);
  float v = a[i];
  if (b) v += b[i];
  out[i] = (v - mr[c]) * mr[128 + c];
}

__global__ __launch_bounds__(256) void k_apply2(const float* __restrict__ a,
                                                const float* __restrict__ b,
                                                const float* __restrict__ mr,
                                                float* __restrict__ outf,
                                                unsigned short* __restrict__ outb) {
  const size_t i = (size_t)blockIdx.x * 256 + threadIdx.x;
  const int c = (int)(i & 127);
  float v = (a[i] + b[i] - mr[c]) * mr[128 + c];
  outf[i] = v;
  outb[i] = f2b(v);
}

__global__ __launch_bounds__(256) void k_apply_t2(const float* __restrict__ a,
                                                  const float* __restrict__ b,
                                                  const float* __restrict__ mr,
                                                  float* __restrict__ out) {
  const size_t i = (size_t)blockIdx.x * 256 + threadIdx.x;  // i = c*16384 + pix
  const int c = (int)(i >> 14);
  const int pix = (int)(i & 16383);
  out[i] = (a[(size_t)pix * 128 + c] + b[(size_t)pix * 128 + c] - mr[c]) * mr[128 + c];
}

extern "C" void kernel_launch(void* const* d_in, const int* in_sizes, int n_in,
                              void* d_out, int out_size, void* d_ws, size_t ws_size,
                              hipStream_t stream) {
  const float* feats = (const float*)d_in[0];
  const float* l2i   = (const float*)d_in[1];
  const float* bevq  = (const float*)d_in[2];
  const float* bpos  = (const float*)d_in[3];
  const float* w_in  = (const float*)d_in[4];
  const float* b_in  = (const float*)d_in[5];
  const float* offw  = (const float*)d_in[6];
  const float* offb  = (const float*)d_in[7];
  const float* w1    = (const float*)d_in[8];
  const float* b1    = (const float*)d_in[9];
  const float* w2    = (const float*)d_in[10];
  const float* b2    = (const float*)d_in[11];
  const float* w3    = (const float*)d_in[12];
  const float* b3    = (const float*)d_in[13];
  const float* w_out = (const float*)d_in[14];
  const float* b_out = (const float*)d_in[15];
  float* out = (float*)d_out;

  const size_t QC = (size_t)QPIX * 128;
  float* ws = (float*)d_ws;
  float* tB = ws;                         // 2,097,152
  float* qC = tB + QC;                    // 2,097,152
  float* x3 = qC + QC;                    // 2,097,152
  float* off = x3 + QC;                   // 196,608
  float* partial = off + 196608;          // 32,768
  float* mr = partial + 32768;            // 256
  float* zerof = mr + 256;                // 160 (zero bias + zero staging src)
  unsigned short* us = (unsigned short*)(zerof + 160);
  unsigned short* S1b = us;               // 8,388,608 (sampled -> x2)
  unsigned short* S2b = S1b + 8388608;    // 8,388,608 (x1)
  unsigned short* featTb = S2b + 8388608; // 2,162,688
  unsigned short* qhi = featTb + 2162688; // 2,097,152 (conv1 hi; later q2 bf16)
  unsigned short* qlo = qhi + 2097152;    // 2,097,152
  unsigned short* w1b = qlo + 2097152;    // 262,144
  unsigned short* w2b = w1b + 262144;     // 262,144
  unsigned short* w3b = w2b + 262144;     // 65,536
  unsigned short* wob = w3b + 65536;      // 147,456
  unsigned short* wibh = wob + 147456;    // 147,456
  unsigned short* wibl = wibh + 147456;   // 147,456
  const unsigned short* zb = (const unsigned short*)zerof;

  dim3 blk(256);
  hipMemsetAsync(zerof, 0, 640, stream);

  // conversions (LDS-tiled transposes + fused weight converts)
  k_t2b<<<dim3(88, 6), blk, 0, stream>>>(feats, featTb, 2816);
  k_t2b_split<<<dim3(512, 1), blk, 0, stream>>>(bevq, qhi, qlo);
  k_wcvt<<<3456, blk, 0, stream>>>(w1, w2, w3, w_out, w_in,
                                   w1b, w2b, w3b, wob, wibh, wibl);

  // t1 = q + conv3x3(q)   (split-precision bf16 MFMA, K split across z)
  mfma_gemm<64, 2, 0, 2, 0><<<dim3(1, 256, 2), blk, 0, stream>>>(
      qhi, qlo, wibh, wibl, b_in, zerof, bevq, tB, x3, 128, 1152, 576, zb);
  k_stats_partial<<<128, blk, 0, stream>>>(tB, x3, partial);
  k_stats_final<<<1, 128, 0, stream>>>(partial, mr);
  k_apply<<<8192, blk, 0, stream>>>(tB, x3, mr, qC);  // qn fp32

  // offset head (parallel) + projection/gather
  k_offsets<<<128, blk, 0, stream>>>(qC, offw, offb, off);
  k_gather<<<QPIX, blk, 0, stream>>>(off, featTb, bpos, l2i, S1b);

  // mid MLP (bf16 MFMA)
  mfma_gemm<128, 0, 1, 0, 1><<<dim3(4, 128, 1), blk, 0, stream>>>(
      S1b, nullptr, w1b, nullptr, b1, zerof, nullptr, S2b, S2b, 512, 512, 512, zb);
  mfma_gemm<128, 0, 1, 0, 1><<<dim3(4, 128, 1), blk, 0, stream>>>(
      S2b, nullptr, w2b, nullptr, b2, zerof, nullptr, S1b, S1b, 512, 512, 512, zb);
  // mm3 K-split; z=0 half carries bias + qn residual
  mfma_gemm<64, 0, 0, 1, 0><<<dim3(1, 256, 2), blk, 0, stream>>>(
      S1b, nullptr, w3b, nullptr, b3, zerof, qC, tB, x3, 128, 512, 256, zb);

  // q2 = inorm(qn + x3)  (qn folded into tB half)
  k_stats_partial<<<128, blk, 0, stream>>>(tB, x3, partial);
  k_stats_final<<<1, 128, 0, stream>>>(partial, mr);
  k_apply2<<<8192, blk, 0, stream>>>(tB, x3, mr, qC, qhi);  // q2 fp32 + bf16

  // t2 = q2 + conv3x3(q2)  (bf16 MFMA im2col, K split)
  mfma_gemm<64, 1, 0, 1, 0><<<dim3(1, 256, 2), blk, 0, stream>>>(
      qhi, nullptr, wob, nullptr, b_out, zerof, qC, tB, x3, 128, 1152, 576, zb);
  k_stats_partial<<<128, blk, 0, stream>>>(tB, x3, partial);
  k_stats_final<<<1, 128, 0, stream>>>(partial, mr);
  k_apply_t2<<<8192, blk, 0, stream>>>(tB, x3, mr, out);
}